// Round 3
// baseline (334.465 us; speedup 1.0000x reference)
//
#include <hip/hip_runtime.h>

#define N_T 8
#define N_CAPS 16
#define CAP_DIM 16
#define HW 4096
#define P_TILE 32
#define ROW_F 36          // padded row stride in floats (144 B; +16B kills bank aliasing)
#define EPS 1e-6f

typedef float vfloat4 __attribute__((ext_vector_type(4)));  // native vec for NT store

// Block: 256 threads, one (b, capsule c) pair x 32 spatial positions.
// LDS: u^2 for 128 (t,d) channels x 32 positions, rows padded: 128*36*4 = 18 KiB.
// 18 KiB -> 8 blocks/CU LDS-limited; VGPR<=64 -> wave-cap (32/CU) is the limit.
__global__ __launch_bounds__(256) void caps_norm_kernel(
    const float* __restrict__ z, const float* __restrict__ u,
    const float* __restrict__ w, const float* __restrict__ beta,
    float* __restrict__ out)
{
    __shared__ float lds[128 * ROW_F];

    const int tid = threadIdx.x;
    const int bid = blockIdx.x;            // ((b*16 + c)*128 + ptile)
    const int ptile = bid & 127;
    const int c     = (bid >> 7) & 15;
    const int b     = bid >> 11;
    const int p0    = ptile * P_TILE;

    float W9[9];
#pragma unroll
    for (int i = 0; i < 9; ++i) W9[i] = w[i];
    const float bet = beta[0];

    const size_t base_b = (size_t)b * 2048 * HW;

    // ---- stage u^2 tile into LDS: 1024 float4 slots, 4 per thread ----
#pragma unroll
    for (int k = 0; k < 4; ++k) {
        int s = tid + k * 256;             // 0..1023
        int r = s >> 3;                    // row = t*16 + d, 0..127
        int q = s & 7;                     // quad within row (8 quads = 32 floats)
        int t = r >> 4, d = r & 15;
        int ch = t * 256 + c * 16 + d;
        const vfloat4 v = *(const vfloat4*)(u + base_b + (size_t)ch * HW + p0 + q * 4);
        *(vfloat4*)(lds + r * ROW_F + q * 4) = v * v;
    }
    __syncthreads();

    // ---- prefetch z quads (expose MLP across the 4 output groups) ----
    vfloat4 z4[4];
    size_t gidx[4];
#pragma unroll
    for (int k = 0; k < 4; ++k) {
        int s = tid + k * 256;
        int r = s >> 3;
        int q = s & 7;
        int t = r >> 4, d = r & 15;
        int ch = t * 256 + c * 16 + d;
        gidx[k] = base_b + (size_t)ch * HW + p0 + q * 4;
        z4[k] = *(const vfloat4*)(z + gidx[k]);
    }

    // ---- 9-point wrapped stencil over (t,d), then (z+beta)*rsqrt ----
#pragma unroll
    for (int k = 0; k < 4; ++k) {
        int s = tid + k * 256;
        int r = s >> 3;
        int q = s & 7;
        int t = r >> 4, d = r & 15;

        vfloat4 acc = (vfloat4)0.f;
#pragma unroll
        for (int i = 0; i < 3; ++i) {
            int tt = (t + i + 7) & 7;
#pragma unroll
            for (int j = 0; j < 3; ++j) {
                int dd = (d + j + 15) & 15;
                float ww = W9[i * 3 + j];
                const vfloat4 a = *(const vfloat4*)(lds + ((tt << 4) + dd) * ROW_F + q * 4);
                acc += ww * a;
            }
        }

        vfloat4 o;
        o.x = (z4[k].x + bet) * rsqrtf(acc.x + EPS);
        o.y = (z4[k].y + bet) * rsqrtf(acc.y + EPS);
        o.z = (z4[k].z + bet) * rsqrtf(acc.z + EPS);
        o.w = (z4[k].w + bet) * rsqrtf(acc.w + EPS);
        __builtin_nontemporal_store(o, (vfloat4*)(out + gidx[k]));
    }
}

extern "C" void kernel_launch(void* const* d_in, const int* in_sizes, int n_in,
                              void* d_out, int out_size, void* d_ws, size_t ws_size,
                              hipStream_t stream) {
    const float* z    = (const float*)d_in[0];
    const float* u    = (const float*)d_in[1];
    const float* w    = (const float*)d_in[2];
    const float* beta = (const float*)d_in[3];
    float* out = (float*)d_out;

    // grid = B(4) * N_CAPS(16) * (HW/P_TILE = 128) = 8192 blocks
    caps_norm_kernel<<<dim3(8192), dim3(256), 0, stream>>>(z, u, w, beta, out);
}